// Round 4
// baseline (249.173 us; speedup 1.0000x reference)
//
#include <hip/hip_runtime.h>

typedef __attribute__((ext_vector_type(8))) short bf16x8;
typedef __attribute__((ext_vector_type(4))) float f32x4;

__device__ __forceinline__ float bf2f(unsigned short u) {
    unsigned int x = ((unsigned int)u) << 16;
    float f;
    __builtin_memcpy(&f, &x, 4);
    return f;
}
__device__ __forceinline__ unsigned short f2bf(float f) {
    unsigned int x;
    __builtin_memcpy(&x, &f, 4);
    x += 0x7FFFu + ((x >> 16) & 1u);
    return (unsigned short)(x >> 16);
}

// Async global->LDS: HW writes lds[base + lane*16]; gptr is per-lane.
#define GLOAD_LDS16(gp, lp)                                      \
    __builtin_amdgcn_global_load_lds(                            \
        (const __attribute__((address_space(1))) void*)(gp),     \
        (__attribute__((address_space(3))) void*)(lp), 16, 0, 0)

// -------------------------------------------------------------------------
// float32 -> bf16 cast, 4 elements/thread
__global__ __launch_bounds__(256) void cast_f32_bf16(
    const float* __restrict__ in, unsigned short* __restrict__ out, int n) {
    int i = (blockIdx.x * 256 + threadIdx.x) * 4;
    if (i >= n) return;
    float4 v = *(const float4*)(in + i);
    out[i + 0] = f2bf(v.x);
    out[i + 1] = f2bf(v.y);
    out[i + 2] = f2bf(v.z);
    out[i + 3] = f2bf(v.w);
}

// -------------------------------------------------------------------------
// W_eff[n][k] = bf16( W[n][k] + (1/16) * sum_r BB[n][r] * A[r][k] ), float32 in.
__global__ __launch_bounds__(256) void fold_lora(
    const float* __restrict__ W, const float* __restrict__ Ain,
    const float* __restrict__ Bin, unsigned short* __restrict__ Weff, int NK) {
    int idx = blockIdx.x * 256 + threadIdx.x;
    if (idx >= NK) return;
    int n = idx >> 10;
    int k = idx & 1023;
    float s = 0.f;
#pragma unroll
    for (int r = 0; r < 16; ++r)
        s += Bin[n * 16 + r] * Ain[r * 1024 + k];
    Weff[idx] = f2bf(W[idx] + 0.0625f * s);
}

// -------------------------------------------------------------------------
// C[M][N] = A[M][K] @ B[N][K]^T + bias[N].  A,B bf16; bias float; fp32 acc.
// m97 structure: global_load_lds width=16 staging, 2 barriers per K-step.
template <bool F32OUT>
__global__ __launch_bounds__(256) void gemm_bt_bias(
    const unsigned short* __restrict__ A, const unsigned short* __restrict__ B,
    const float* __restrict__ bias, unsigned short* __restrict__ Cb,
    float* __restrict__ Cf, int M, int N, int K) {
    __shared__ unsigned short sA[128 * 32];
    __shared__ unsigned short sB[128 * 32];
    const int tid = threadIdx.x;
    const int wave = tid >> 6, lane = tid & 63;
    const int quad = lane >> 4, l16 = lane & 15;
    const int m0 = blockIdx.y * 128, n0 = blockIdx.x * 128;
    const int wm = (wave & 1) * 64, wn = (wave >> 1) * 64;

    const int srow = wave * 32 + (lane >> 2);
    const int scol = (lane & 3) * 8;
    const unsigned short* Ag = A + (size_t)(m0 + srow) * K + scol;
    const unsigned short* Bg = B + (size_t)(n0 + srow) * K + scol;
    unsigned short* sAw = sA + wave * 1024;
    unsigned short* sBw = sB + wave * 1024;
    const size_t kjump = (size_t)16 * K;

    f32x4 acc[4][4];
#pragma unroll
    for (int i = 0; i < 4; ++i)
#pragma unroll
        for (int j = 0; j < 4; ++j) acc[i][j] = (f32x4){0.f, 0.f, 0.f, 0.f};

    for (int k0 = 0; k0 < K; k0 += 32) {
        __syncthreads();  // previous tile's LDS reads done
        GLOAD_LDS16(Ag + k0, sAw);
        GLOAD_LDS16(Ag + k0 + kjump, sAw + 512);
        GLOAD_LDS16(Bg + k0, sBw);
        GLOAD_LDS16(Bg + k0 + kjump, sBw + 512);
        __syncthreads();  // drains vmcnt(0): tile resident
        bf16x8 af[4], bfr[4];
#pragma unroll
        for (int mi = 0; mi < 4; ++mi)
            af[mi] = *(const bf16x8*)&sA[(wm + mi * 16 + l16) * 32 + quad * 8];
#pragma unroll
        for (int ni = 0; ni < 4; ++ni)
            bfr[ni] = *(const bf16x8*)&sB[(wn + ni * 16 + l16) * 32 + quad * 8];
#pragma unroll
        for (int mi = 0; mi < 4; ++mi)
#pragma unroll
            for (int ni = 0; ni < 4; ++ni)
                acc[mi][ni] = __builtin_amdgcn_mfma_f32_16x16x32_bf16(
                    af[mi], bfr[ni], acc[mi][ni], 0, 0, 0);
    }
    float bv[4];
#pragma unroll
    for (int ni = 0; ni < 4; ++ni) bv[ni] = bias[n0 + wn + ni * 16 + l16];
#pragma unroll
    for (int mi = 0; mi < 4; ++mi)
#pragma unroll
        for (int ni = 0; ni < 4; ++ni)
#pragma unroll
            for (int r = 0; r < 4; ++r) {
                int row = m0 + wm + mi * 16 + quad * 4 + r;
                int col = n0 + wn + ni * 16 + l16;
                float val = acc[mi][ni][r] + bv[ni];
                if (F32OUT)
                    Cf[(size_t)row * N + col] = val;
                else
                    Cb[(size_t)row * N + col] = f2bf(val);
            }
}

// -------------------------------------------------------------------------
// Vt[(b*16+h)][d][t] = qkv[b*2048+t][2048 + h*64 + d]   (bf16, verified r3)
__global__ __launch_bounds__(256) void transpose_v(
    const unsigned short* __restrict__ qkv, unsigned short* __restrict__ Vt) {
    const int b = blockIdx.z, h = blockIdx.y, t0 = blockIdx.x * 64;
    __shared__ unsigned short tile[64][68];
    const int tid = threadIdx.x;
    const int r = tid >> 3, c8 = (tid & 7) * 8;
    const unsigned short* src = qkv + (size_t)(b * 2048) * 3072 + 2048 + h * 64;
#pragma unroll
    for (int p = 0; p < 2; ++p) {
        int t = p * 32 + r;
        const unsigned short* s = src + (size_t)(t0 + t) * 3072 + c8;
#pragma unroll
        for (int j = 0; j < 8; ++j) tile[t][c8 + j] = s[j];
    }
    __syncthreads();
    unsigned short* dst = Vt + (size_t)((b * 16 + h) * 64) * 2048;
#pragma unroll
    for (int p = 0; p < 2; ++p) {
        int d = p * 32 + r;
        unsigned short* o = dst + (size_t)d * 2048 + t0 + c8;
#pragma unroll
        for (int j = 0; j < 8; ++j) o[j] = tile[c8 + j][d];
    }
}

// -------------------------------------------------------------------------
// Flash attention v6: split-KV partials.
// No online max => partials are purely additive: o = sum exp2(S*csc)*V,
// l = sum exp2(S*csc). Each (b,h,qblk) is split into 2 blocks covering
// kv tiles [0,half) and [half,ntiles); each writes f32 partial (o, l).
// Grid x = 64 (qblk descending, parts adjacent) -> 2048 blocks total vs
// ~1280 resident slots (5 blocks/CU by LDS): the HW scheduler refills
// freed slots = dynamic load balancing; critical path is 16 tiles (was 32).
// attn_finalize combines: y = bf16((o0+o1)/(l0+l1)).
__global__ __launch_bounds__(256) void attn_partial(
    const unsigned short* __restrict__ qkv,  // [4096][3072] bf16
    const unsigned short* __restrict__ Vt,   // [32][64][2048] bf16
    float* __restrict__ opart,               // [2][4096][1024] f32
    float* __restrict__ lpart) {             // [2][32][2048] f32
    const int b = blockIdx.z, h = blockIdx.y;
    const int bh = b * 16 + h;
    const int idx = blockIdx.x;        // 0..63
    const int qblk = 31 - (idx >> 1);  // longest first
    const int part = idx & 1;
    const int w = threadIdx.x >> 6, lane = threadIdx.x & 63;
    const int quad = lane >> 4, l16 = lane & 15;
    const int q0 = qblk * 64 + w * 16;
    const int ntiles = qblk + 1;
    const int half = (ntiles + 1) >> 1;
    const int lo = part ? half : 0;
    const int hi = part ? ntiles : half;

    float* op = opart + (size_t)part * 4096 * 1024;
    float* lp = lpart + (size_t)part * 32 * 2048;
    float* ob = op + (size_t)(b * 2048) * 1024 + h * 64;

    if (lo >= hi) {  // empty half (qblk==0, part 1): write zero partials
#pragma unroll
        for (int nt = 0; nt < 4; ++nt)
#pragma unroll
            for (int r = 0; r < 4; ++r)
                ob[(size_t)(q0 + quad * 4 + r) * 1024 + nt * 16 + l16] = 0.f;
        if (l16 == 0)
#pragma unroll
            for (int r = 0; r < 4; ++r) lp[bh * 2048 + q0 + quad * 4 + r] = 0.f;
        return;
    }

    __shared__ unsigned short sK[64 * 72];     // [kv][d]
    __shared__ unsigned short sV[64 * 72];     // [d][kv]
    __shared__ unsigned short sP[4][16 * 72];  // per-wave P [q][kv]

    const unsigned short* Qb = qkv + (size_t)(b * 2048) * 3072 + h * 64;
    const unsigned short* Kg = Qb + 1024;
    const unsigned short* Vg = Vt + (size_t)(bh * 64) * 2048;

    const int rlo = threadIdx.x >> 3;       // 0..31
    const int c8 = (threadIdx.x & 7) * 8;   // 0..56

    bf16x8 qf0 = *(const bf16x8*)(Qb + (size_t)(q0 + l16) * 3072 + quad * 8);
    bf16x8 qf1 = *(const bf16x8*)(Qb + (size_t)(q0 + l16) * 3072 + 32 + quad * 8);

    f32x4 o[4];
    float lacc[4];
#pragma unroll
    for (int nt = 0; nt < 4; ++nt) o[nt] = (f32x4){0.f, 0.f, 0.f, 0.f};
#pragma unroll
    for (int r = 0; r < 4; ++r) lacc[r] = 0.f;

    const float csc = 0.125f * 1.44269504088896340736f;  // (1/sqrt 64)*log2(e)

    const int kvlo = lo * 64;
    bf16x8 kr0 = *(const bf16x8*)(Kg + (size_t)(kvlo + rlo) * 3072 + c8);
    bf16x8 kr1 = *(const bf16x8*)(Kg + (size_t)(kvlo + rlo + 32) * 3072 + c8);
    bf16x8 vr0 = *(const bf16x8*)(Vg + (size_t)rlo * 2048 + kvlo + c8);
    bf16x8 vr1 = *(const bf16x8*)(Vg + (size_t)(rlo + 32) * 2048 + kvlo + c8);

    for (int it = lo; it < hi; ++it) {
        const int kv0 = it * 64;
        __syncthreads();  // buffer free
        *(bf16x8*)&sK[rlo * 72 + c8] = kr0;
        *(bf16x8*)&sK[(rlo + 32) * 72 + c8] = kr1;
        *(bf16x8*)&sV[rlo * 72 + c8] = vr0;
        *(bf16x8*)&sV[(rlo + 32) * 72 + c8] = vr1;
        if (it + 1 < hi) {  // prefetch next tile; overlaps compute below
            const int nx = kv0 + 64;
            kr0 = *(const bf16x8*)(Kg + (size_t)(nx + rlo) * 3072 + c8);
            kr1 = *(const bf16x8*)(Kg + (size_t)(nx + rlo + 32) * 3072 + c8);
            vr0 = *(const bf16x8*)(Vg + (size_t)rlo * 2048 + nx + c8);
            vr1 = *(const bf16x8*)(Vg + (size_t)(rlo + 32) * 2048 + nx + c8);
        }
        __syncthreads();  // buffer ready

        f32x4 S[4];
#pragma unroll
        for (int f = 0; f < 4; ++f) {
            bf16x8 klo = *(const bf16x8*)&sK[(f * 16 + l16) * 72 + quad * 8];
            bf16x8 khi = *(const bf16x8*)&sK[(f * 16 + l16) * 72 + 32 + quad * 8];
            S[f] = (f32x4){0.f, 0.f, 0.f, 0.f};
            S[f] = __builtin_amdgcn_mfma_f32_16x16x32_bf16(qf0, klo, S[f], 0, 0, 0);
            S[f] = __builtin_amdgcn_mfma_f32_16x16x32_bf16(qf1, khi, S[f], 0, 0, 0);
        }
        if (it == qblk) {  // only the diagonal tile needs the causal mask
#pragma unroll
            for (int f = 0; f < 4; ++f)
#pragma unroll
                for (int r = 0; r < 4; ++r) {
                    int col = kv0 + f * 16 + l16;
                    int qr = q0 + quad * 4 + r;
                    float p = (col <= qr) ? exp2f(S[f][r] * csc) : 0.f;
                    lacc[r] += p;
                    sP[w][(quad * 4 + r) * 72 + f * 16 + l16] = f2bf(p);
                }
        } else {
#pragma unroll
            for (int f = 0; f < 4; ++f)
#pragma unroll
                for (int r = 0; r < 4; ++r) {
                    float p = exp2f(S[f][r] * csc);
                    lacc[r] += p;
                    sP[w][(quad * 4 + r) * 72 + f * 16 + l16] = f2bf(p);
                }
        }
        asm volatile("" ::: "memory");  // order P stores before reload
        bf16x8 pf0 = *(const bf16x8*)&sP[w][l16 * 72 + quad * 8];
        bf16x8 pf1 = *(const bf16x8*)&sP[w][l16 * 72 + 32 + quad * 8];
#pragma unroll
        for (int nt = 0; nt < 4; ++nt) {
            bf16x8 v0 = *(const bf16x8*)&sV[(nt * 16 + l16) * 72 + quad * 8];
            bf16x8 v1 = *(const bf16x8*)&sV[(nt * 16 + l16) * 72 + 32 + quad * 8];
            o[nt] = __builtin_amdgcn_mfma_f32_16x16x32_bf16(pf0, v0, o[nt], 0, 0, 0);
            o[nt] = __builtin_amdgcn_mfma_f32_16x16x32_bf16(pf1, v1, o[nt], 0, 0, 0);
        }
    }

    float lt[4];
#pragma unroll
    for (int r = 0; r < 4; ++r) lt[r] = lacc[r];
#pragma unroll
    for (int d = 1; d < 16; d <<= 1)
#pragma unroll
        for (int r = 0; r < 4; ++r) lt[r] += __shfl_xor(lt[r], d);

    if (l16 == 0)
#pragma unroll
        for (int r = 0; r < 4; ++r) lp[bh * 2048 + q0 + quad * 4 + r] = lt[r];
#pragma unroll
    for (int nt = 0; nt < 4; ++nt)
#pragma unroll
        for (int r = 0; r < 4; ++r)
            ob[(size_t)(q0 + quad * 4 + r) * 1024 + nt * 16 + l16] = o[nt][r];
}

// -------------------------------------------------------------------------
// y[row][c] = bf16((o0+o1)/(l0+l1)); rows = b*2048+t, c = h*64+d.
__global__ __launch_bounds__(256) void attn_finalize(
    const float* __restrict__ opart, const float* __restrict__ lpart,
    unsigned short* __restrict__ y) {
    int i = (blockIdx.x * 256 + threadIdx.x) * 4;  // over 4096*1024
    float4 a = *(const float4*)(opart + i);
    float4 b4 = *(const float4*)(opart + (size_t)4096 * 1024 + i);
    int row = i >> 10;
    int c = i & 1023;
    int bh = (row >> 11) * 16 + (c >> 6);
    int q = row & 2047;
    float l = lpart[bh * 2048 + q] + lpart[32 * 2048 + bh * 2048 + q];
    float inv = 1.f / l;
    y[i + 0] = f2bf((a.x + b4.x) * inv);
    y[i + 1] = f2bf((a.y + b4.y) * inv);
    y[i + 2] = f2bf((a.z + b4.z) * inv);
    y[i + 3] = f2bf((a.w + b4.w) * inv);
}

// -------------------------------------------------------------------------
extern "C" void kernel_launch(void* const* d_in, const int* in_sizes, int n_in,
                              void* d_out, int out_size, void* d_ws, size_t ws_size,
                              hipStream_t stream) {
    const float* x       = (const float*)d_in[0];
    const float* w_attn  = (const float*)d_in[1];
    const float* b_attn  = (const float*)d_in[2];
    const float* la_attn = (const float*)d_in[3];
    const float* lb_attn = (const float*)d_in[4];
    const float* w_proj  = (const float*)d_in[5];
    const float* b_proj  = (const float*)d_in[6];
    const float* la_proj = (const float*)d_in[7];
    const float* lb_proj = (const float*)d_in[8];
    float* out = (float*)d_out;

    char* w = (char*)d_ws;
    unsigned short* xb        = (unsigned short*)w; w += (size_t)4096 * 1024 * 2;
    unsigned short* Weff_attn = (unsigned short*)w; w += (size_t)3072 * 1024 * 2;
    unsigned short* Weff_proj = (unsigned short*)w; w += (size_t)1024 * 1024 * 2;
    unsigned short* qkv       = (unsigned short*)w; w += (size_t)4096 * 3072 * 2;
    unsigned short* Vt        = (unsigned short*)w; w += (size_t)32 * 64 * 2048 * 2;
    unsigned short* y         = (unsigned short*)w; w += (size_t)4096 * 1024 * 2;
    float* opart              = (float*)w;          w += (size_t)2 * 4096 * 1024 * 4;
    float* lpart              = (float*)w;          w += (size_t)2 * 32 * 2048 * 4;

    cast_f32_bf16<<<4096, 256, 0, stream>>>(x, xb, 4096 * 1024);
    fold_lora<<<(3072 * 1024) / 256, 256, 0, stream>>>(w_attn, la_attn, lb_attn,
                                                       Weff_attn, 3072 * 1024);
    fold_lora<<<(1024 * 1024) / 256, 256, 0, stream>>>(w_proj, la_proj, lb_proj,
                                                       Weff_proj, 1024 * 1024);
    gemm_bt_bias<false><<<dim3(24, 32), 256, 0, stream>>>(
        xb, Weff_attn, b_attn, qkv, (float*)nullptr, 4096, 3072, 1024);
    transpose_v<<<dim3(32, 16, 2), 256, 0, stream>>>(qkv, Vt);
    attn_partial<<<dim3(64, 16, 2), 256, 0, stream>>>(qkv, Vt, opart, lpart);
    attn_finalize<<<4096, 256, 0, stream>>>(opart, lpart, y);
    gemm_bt_bias<true><<<dim3(8, 32), 256, 0, stream>>>(
        y, Weff_proj, b_proj, (unsigned short*)nullptr, out, 4096, 1024, 1024);
}

// Round 5
// 210.765 us; speedup vs baseline: 1.1822x; 1.1822x over previous
//
#include <hip/hip_runtime.h>

typedef __attribute__((ext_vector_type(8))) short bf16x8;
typedef __attribute__((ext_vector_type(4))) float f32x4;

__device__ __forceinline__ float bf2f(unsigned short u) {
    unsigned int x = ((unsigned int)u) << 16;
    float f;
    __builtin_memcpy(&f, &x, 4);
    return f;
}
__device__ __forceinline__ unsigned short f2bf(float f) {
    unsigned int x;
    __builtin_memcpy(&x, &f, 4);
    x += 0x7FFFu + ((x >> 16) & 1u);
    return (unsigned short)(x >> 16);
}

// Async global->LDS: HW writes lds[base + lane*16]; gptr is per-lane.
#define GLOAD_LDS16(gp, lp)                                      \
    __builtin_amdgcn_global_load_lds(                            \
        (const __attribute__((address_space(1))) void*)(gp),     \
        (__attribute__((address_space(3))) void*)(lp), 16, 0, 0)

// -------------------------------------------------------------------------
// Fused preprocessing: one launch instead of three.
// blocks [0,4096):        cast x f32 -> bf16 (4 elems/thread)
// blocks [4096,16384):    fold_lora attn  (3072x1024)
// blocks [16384,20480):   fold_lora proj  (1024x1024)
__global__ __launch_bounds__(256) void prep(
    const float* __restrict__ x, unsigned short* __restrict__ xb,
    const float* __restrict__ w_attn, const float* __restrict__ la_attn,
    const float* __restrict__ lb_attn, unsigned short* __restrict__ Weff_attn,
    const float* __restrict__ w_proj, const float* __restrict__ la_proj,
    const float* __restrict__ lb_proj, unsigned short* __restrict__ Weff_proj) {
    const int bid = blockIdx.x;
    if (bid < 4096) {
        int i = (bid * 256 + threadIdx.x) * 4;
        float4 v = *(const float4*)(x + i);
        xb[i + 0] = f2bf(v.x);
        xb[i + 1] = f2bf(v.y);
        xb[i + 2] = f2bf(v.z);
        xb[i + 3] = f2bf(v.w);
        return;
    }
    const float* W;
    const float* Ain;
    const float* Bin;
    unsigned short* Weff;
    int idx;
    if (bid < 16384) {
        idx = (bid - 4096) * 256 + threadIdx.x;
        W = w_attn; Ain = la_attn; Bin = lb_attn; Weff = Weff_attn;
    } else {
        idx = (bid - 16384) * 256 + threadIdx.x;
        W = w_proj; Ain = la_proj; Bin = lb_proj; Weff = Weff_proj;
    }
    int n = idx >> 10;
    int k = idx & 1023;
    float s = 0.f;
#pragma unroll
    for (int r = 0; r < 16; ++r)
        s += Bin[n * 16 + r] * Ain[r * 1024 + k];
    Weff[idx] = f2bf(W[idx] + 0.0625f * s);
}

// -------------------------------------------------------------------------
// C[M][N] = A[M][K] @ B[N][K]^T + bias[N].  A,B bf16; bias float; fp32 acc.
// m97 structure: global_load_lds width=16 staging, 2 barriers per K-step.
template <bool F32OUT>
__global__ __launch_bounds__(256) void gemm_bt_bias(
    const unsigned short* __restrict__ A, const unsigned short* __restrict__ B,
    const float* __restrict__ bias, unsigned short* __restrict__ Cb,
    float* __restrict__ Cf, int M, int N, int K) {
    __shared__ unsigned short sA[128 * 32];
    __shared__ unsigned short sB[128 * 32];
    const int tid = threadIdx.x;
    const int wave = tid >> 6, lane = tid & 63;
    const int quad = lane >> 4, l16 = lane & 15;
    const int m0 = blockIdx.y * 128, n0 = blockIdx.x * 128;
    const int wm = (wave & 1) * 64, wn = (wave >> 1) * 64;

    const int srow = wave * 32 + (lane >> 2);
    const int scol = (lane & 3) * 8;
    const unsigned short* Ag = A + (size_t)(m0 + srow) * K + scol;
    const unsigned short* Bg = B + (size_t)(n0 + srow) * K + scol;
    unsigned short* sAw = sA + wave * 1024;
    unsigned short* sBw = sB + wave * 1024;
    const size_t kjump = (size_t)16 * K;

    f32x4 acc[4][4];
#pragma unroll
    for (int i = 0; i < 4; ++i)
#pragma unroll
        for (int j = 0; j < 4; ++j) acc[i][j] = (f32x4){0.f, 0.f, 0.f, 0.f};

    for (int k0 = 0; k0 < K; k0 += 32) {
        __syncthreads();  // previous tile's LDS reads done
        GLOAD_LDS16(Ag + k0, sAw);
        GLOAD_LDS16(Ag + k0 + kjump, sAw + 512);
        GLOAD_LDS16(Bg + k0, sBw);
        GLOAD_LDS16(Bg + k0 + kjump, sBw + 512);
        __syncthreads();  // drains vmcnt(0): tile resident
        bf16x8 af[4], bfr[4];
#pragma unroll
        for (int mi = 0; mi < 4; ++mi)
            af[mi] = *(const bf16x8*)&sA[(wm + mi * 16 + l16) * 32 + quad * 8];
#pragma unroll
        for (int ni = 0; ni < 4; ++ni)
            bfr[ni] = *(const bf16x8*)&sB[(wn + ni * 16 + l16) * 32 + quad * 8];
#pragma unroll
        for (int mi = 0; mi < 4; ++mi)
#pragma unroll
            for (int ni = 0; ni < 4; ++ni)
                acc[mi][ni] = __builtin_amdgcn_mfma_f32_16x16x32_bf16(
                    af[mi], bfr[ni], acc[mi][ni], 0, 0, 0);
    }
    float bv[4];
#pragma unroll
    for (int ni = 0; ni < 4; ++ni) bv[ni] = bias[n0 + wn + ni * 16 + l16];
#pragma unroll
    for (int mi = 0; mi < 4; ++mi)
#pragma unroll
        for (int ni = 0; ni < 4; ++ni)
#pragma unroll
            for (int r = 0; r < 4; ++r) {
                int row = m0 + wm + mi * 16 + quad * 4 + r;
                int col = n0 + wn + ni * 16 + l16;
                float val = acc[mi][ni][r] + bv[ni];
                if (F32OUT)
                    Cf[(size_t)row * N + col] = val;
                else
                    Cb[(size_t)row * N + col] = f2bf(val);
            }
}

// -------------------------------------------------------------------------
// Vt[(b*16+h)][d][t] = qkv[b*2048+t][2048 + h*64 + d]   (bf16, verified r3)
__global__ __launch_bounds__(256) void transpose_v(
    const unsigned short* __restrict__ qkv, unsigned short* __restrict__ Vt) {
    const int b = blockIdx.z, h = blockIdx.y, t0 = blockIdx.x * 64;
    __shared__ unsigned short tile[64][68];
    const int tid = threadIdx.x;
    const int r = tid >> 3, c8 = (tid & 7) * 8;
    const unsigned short* src = qkv + (size_t)(b * 2048) * 3072 + 2048 + h * 64;
#pragma unroll
    for (int p = 0; p < 2; ++p) {
        int t = p * 32 + r;
        const unsigned short* s = src + (size_t)(t0 + t) * 3072 + c8;
#pragma unroll
        for (int j = 0; j < 8; ++j) tile[t][c8 + j] = s[j];
    }
    __syncthreads();
    unsigned short* dst = Vt + (size_t)((b * 16 + h) * 64) * 2048;
#pragma unroll
    for (int p = 0; p < 2; ++p) {
        int d = p * 32 + r;
        unsigned short* o = dst + (size_t)d * 2048 + t0 + c8;
#pragma unroll
        for (int j = 0; j < 8; ++j) o[j] = tile[c8 + j][d];
    }
}

// -------------------------------------------------------------------------
// Flash attention v7: r3 scheduling (balanced qblk permutation, grid 32) +
// swapped-QK^T softmax (T12-derived).
// S^T = mfma(K_frag, Q_frag): thread (quad,l16) holds S for q = q0+l16,
// kv = kv0 + f*16 + quad*4 + {0..3} -- 4 ADJACENT kv per f. Softmax becomes:
// v_exp_f32, pack 4 bf16 via 2x v_cvt_pk_bf16_f32, ONE ds_write_b64 per f
// (was 16 scalar ds_write_b16 per thread), scalar denom accumulator.
// PV (A-frag read of sP rows), V path, staging, epilogue: unchanged.
__global__ __launch_bounds__(256) void attn_kernel(
    const unsigned short* __restrict__ qkv,  // [4096][3072] bf16
    const unsigned short* __restrict__ Vt,   // [32][64][2048] bf16
    unsigned short* __restrict__ y) {        // [4096][1024] bf16
    const int b = blockIdx.z, h = blockIdx.y;
    const int bh = b * 16 + h;
    const int qblk = (int)blockIdx.x ^ (((bh >> 3) & 1) ? 31 : 0);
    const int w = threadIdx.x >> 6, lane = threadIdx.x & 63;
    const int quad = lane >> 4, l16 = lane & 15;
    const int q0 = qblk * 64 + w * 16;
    const int ntiles = qblk + 1;

    __shared__ unsigned short sK[64 * 72];     // [kv][d]
    __shared__ unsigned short sV[64 * 72];     // [d][kv]
    __shared__ unsigned short sP[4][16 * 72];  // per-wave P [q][kv]

    const unsigned short* Qb = qkv + (size_t)(b * 2048) * 3072 + h * 64;
    const unsigned short* Kg = Qb + 1024;
    const unsigned short* Vg = Vt + (size_t)(bh * 64) * 2048;

    const int rlo = threadIdx.x >> 3;       // 0..31
    const int c8 = (threadIdx.x & 7) * 8;   // 0..56

    bf16x8 qf0 = *(const bf16x8*)(Qb + (size_t)(q0 + l16) * 3072 + quad * 8);
    bf16x8 qf1 = *(const bf16x8*)(Qb + (size_t)(q0 + l16) * 3072 + 32 + quad * 8);

    f32x4 o[4];
    float lacc = 0.f;  // scalar: all this thread's P values belong to q=q0+l16
#pragma unroll
    for (int nt = 0; nt < 4; ++nt) o[nt] = (f32x4){0.f, 0.f, 0.f, 0.f};

    const float csc = 0.125f * 1.44269504088896340736f;  // (1/sqrt 64)*log2(e)

    bf16x8 kr0 = *(const bf16x8*)(Kg + (size_t)rlo * 3072 + c8);
    bf16x8 kr1 = *(const bf16x8*)(Kg + (size_t)(rlo + 32) * 3072 + c8);
    bf16x8 vr0 = *(const bf16x8*)(Vg + (size_t)rlo * 2048 + c8);
    bf16x8 vr1 = *(const bf16x8*)(Vg + (size_t)(rlo + 32) * 2048 + c8);

    for (int it = 0; it < ntiles; ++it) {
        const int kv0 = it * 64;
        __syncthreads();  // buffer free
        *(bf16x8*)&sK[rlo * 72 + c8] = kr0;
        *(bf16x8*)&sK[(rlo + 32) * 72 + c8] = kr1;
        *(bf16x8*)&sV[rlo * 72 + c8] = vr0;
        *(bf16x8*)&sV[(rlo + 32) * 72 + c8] = vr1;
        if (it + 1 < ntiles) {  // prefetch next tile; overlaps compute below
            const int nx = kv0 + 64;
            kr0 = *(const bf16x8*)(Kg + (size_t)(nx + rlo) * 3072 + c8);
            kr1 = *(const bf16x8*)(Kg + (size_t)(nx + rlo + 32) * 3072 + c8);
            vr0 = *(const bf16x8*)(Vg + (size_t)rlo * 2048 + nx + c8);
            vr1 = *(const bf16x8*)(Vg + (size_t)(rlo + 32) * 2048 + nx + c8);
        }
        __syncthreads();  // buffer ready

        // S^T[f][r]: q = q0+l16, kv = kv0 + f*16 + quad*4 + r
        f32x4 S[4];
#pragma unroll
        for (int f = 0; f < 4; ++f) {
            bf16x8 klo = *(const bf16x8*)&sK[(f * 16 + l16) * 72 + quad * 8];
            bf16x8 khi = *(const bf16x8*)&sK[(f * 16 + l16) * 72 + 32 + quad * 8];
            S[f] = (f32x4){0.f, 0.f, 0.f, 0.f};
            S[f] = __builtin_amdgcn_mfma_f32_16x16x32_bf16(klo, qf0, S[f], 0, 0, 0);
            S[f] = __builtin_amdgcn_mfma_f32_16x16x32_bf16(khi, qf1, S[f], 0, 0, 0);
        }
        const bool diag = (it == qblk);
        const int qr16 = w * 16 + l16;  // q position within the 64-row block
#pragma unroll
        for (int f = 0; f < 4; ++f) {
            float p0, p1, p2, p3;
            {
                float sv = S[f][0] * csc;
                asm("v_exp_f32 %0, %1" : "=v"(p0) : "v"(sv));
                sv = S[f][1] * csc;
                asm("v_exp_f32 %0, %1" : "=v"(p1) : "v"(sv));
                sv = S[f][2] * csc;
                asm("v_exp_f32 %0, %1" : "=v"(p2) : "v"(sv));
                sv = S[f][3] * csc;
                asm("v_exp_f32 %0, %1" : "=v"(p3) : "v"(sv));
            }
            if (diag) {  // mask: kv_local <= q_local
                int c = f * 16 + quad * 4;
                p0 = (c + 0 <= qr16) ? p0 : 0.f;
                p1 = (c + 1 <= qr16) ? p1 : 0.f;
                p2 = (c + 2 <= qr16) ? p2 : 0.f;
                p3 = (c + 3 <= qr16) ? p3 : 0.f;
            }
            lacc += (p0 + p1) + (p2 + p3);
            unsigned int d0, d1;
            asm("v_cvt_pk_bf16_f32 %0, %1, %2" : "=v"(d0) : "v"(p0), "v"(p1));
            asm("v_cvt_pk_bf16_f32 %0, %1, %2" : "=v"(d1) : "v"(p2), "v"(p3));
            *(uint2*)&sP[w][l16 * 72 + f * 16 + quad * 4] = (uint2){d0, d1};
        }
        asm volatile("" ::: "memory");  // order P stores before reload
        bf16x8 pf0 = *(const bf16x8*)&sP[w][l16 * 72 + quad * 8];
        bf16x8 pf1 = *(const bf16x8*)&sP[w][l16 * 72 + 32 + quad * 8];
#pragma unroll
        for (int nt = 0; nt < 4; ++nt) {
            bf16x8 v0 = *(const bf16x8*)&sV[(nt * 16 + l16) * 72 + quad * 8];
            bf16x8 v1 = *(const bf16x8*)&sV[(nt * 16 + l16) * 72 + 32 + quad * 8];
            o[nt] = __builtin_amdgcn_mfma_f32_16x16x32_bf16(pf0, v0, o[nt], 0, 0, 0);
            o[nt] = __builtin_amdgcn_mfma_f32_16x16x32_bf16(pf1, v1, o[nt], 0, 0, 0);
        }
    }

    // lacc holds a partial denom for q=q0+l16 (this thread's kv subset).
    // Full denom: sum over the 4 quads (lanes sharing l16).
    lacc += __shfl_xor(lacc, 16);
    lacc += __shfl_xor(lacc, 32);
    // Output rows of this thread are q0 + quad*4 + r; their denoms live in
    // lanes (quad*4+r) (which have l16 == quad*4+r).
    float lt[4];
#pragma unroll
    for (int r = 0; r < 4; ++r) lt[r] = __shfl(lacc, quad * 4 + r);

    unsigned short* yb = y + (size_t)(b * 2048) * 1024 + h * 64;
#pragma unroll
    for (int nt = 0; nt < 4; ++nt)
#pragma unroll
        for (int r = 0; r < 4; ++r)
            yb[(size_t)(q0 + quad * 4 + r) * 1024 + nt * 16 + l16] =
                f2bf(o[nt][r] / lt[r]);
}

// -------------------------------------------------------------------------
extern "C" void kernel_launch(void* const* d_in, const int* in_sizes, int n_in,
                              void* d_out, int out_size, void* d_ws, size_t ws_size,
                              hipStream_t stream) {
    const float* x       = (const float*)d_in[0];
    const float* w_attn  = (const float*)d_in[1];
    const float* b_attn  = (const float*)d_in[2];
    const float* la_attn = (const float*)d_in[3];
    const float* lb_attn = (const float*)d_in[4];
    const float* w_proj  = (const float*)d_in[5];
    const float* b_proj  = (const float*)d_in[6];
    const float* la_proj = (const float*)d_in[7];
    const float* lb_proj = (const float*)d_in[8];
    float* out = (float*)d_out;

    char* w = (char*)d_ws;
    unsigned short* xb        = (unsigned short*)w; w += (size_t)4096 * 1024 * 2;
    unsigned short* Weff_attn = (unsigned short*)w; w += (size_t)3072 * 1024 * 2;
    unsigned short* Weff_proj = (unsigned short*)w; w += (size_t)1024 * 1024 * 2;
    unsigned short* qkv       = (unsigned short*)w; w += (size_t)4096 * 3072 * 2;
    unsigned short* Vt        = (unsigned short*)w; w += (size_t)32 * 64 * 2048 * 2;
    unsigned short* y         = (unsigned short*)w; w += (size_t)4096 * 1024 * 2;

    prep<<<20480, 256, 0, stream>>>(x, xb, w_attn, la_attn, lb_attn, Weff_attn,
                                    w_proj, la_proj, lb_proj, Weff_proj);
    gemm_bt_bias<false><<<dim3(24, 32), 256, 0, stream>>>(
        xb, Weff_attn, b_attn, qkv, (float*)nullptr, 4096, 3072, 1024);
    transpose_v<<<dim3(32, 16, 2), 256, 0, stream>>>(qkv, Vt);
    attn_kernel<<<dim3(32, 16, 2), 256, 0, stream>>>(qkv, Vt, y);
    gemm_bt_bias<true><<<dim3(8, 32), 256, 0, stream>>>(
        y, Weff_proj, b_proj, (unsigned short*)nullptr, out, 4096, 1024, 1024);
}